// Round 10
// baseline (387.121 us; speedup 1.0000x reference)
//
#include <hip/hip_runtime.h>

// DiT block, B=4 N=512 D=1024 H=16 HD=64 HID=4096 RP_HID=64. All f32 I/O.
// R10: un-fuse the LDS-heavy bias from the streaming converts (R9 regression:
//      one 48KB-LDS profile starved the copy sections). k_cvtmod = cvts+mod
//      (4KB LDS, full occupancy); k_bias standalone. 10 launches.
// ws (byte off): mod@0(128K) | xn@128K(4M) | xm@+4M(8M) | wqkvb@+12M(6M) |
//   wprojb@+18M(2M) | wfc1b@+20M(8M) | wfc2b@+28M(8M) | qkvb@+36M(12M) |
//   biasb@+48M(32M) | hb@+80M(16M) | parts@+96M(16M)

#define B_ 4
#define N_ 512
#define D_ 1024
#define H_ 16
#define HID_ 4096
#define M_ (B_*N_)

typedef unsigned short u16;
typedef __attribute__((ext_vector_type(8))) short bf16x8;
typedef __attribute__((ext_vector_type(4))) float f32x4;

__device__ __forceinline__ float b2f(u16 u){
  union { unsigned int i; float f; } x; x.i = ((unsigned int)u) << 16; return x.f;
}
__device__ __forceinline__ u16 f2b(float f){          // RNE
  unsigned int u = __float_as_uint(f);
  return (u16)((u + 0x7fffu + ((u >> 16) & 1u)) >> 16);
}

__device__ __forceinline__ void gload16(const u16* __restrict__ g, u16* l){
#if defined(__has_builtin) && __has_builtin(__builtin_amdgcn_global_load_lds)
  __builtin_amdgcn_global_load_lds(
      (const __attribute__((address_space(1))) unsigned int*)g,
      (__attribute__((address_space(3))) unsigned int*)l, 16, 0, 0);
#else
  *(uint4*)l = *(const uint4*)g;
#endif
}

// ---------------- converts (no LDS) + adaLN mod (4KB LDS): one launch
// [0,1536) w_qkv | [1536,2048) w_proj | [2048,4096) w_fc1 | [4096,6144) w_fc2
// [6144,6240) mod (24 jblk x 4 b)
__global__ __launch_bounds__(256) void k_cvtmod(
    const float* __restrict__ w_qkv, u16* __restrict__ wqkvb,
    const float* __restrict__ w_proj, u16* __restrict__ wprojb,
    const float* __restrict__ w_fc1, u16* __restrict__ wfc1b,
    const float* __restrict__ w_fc2, u16* __restrict__ wfc2b,
    const float* __restrict__ t_emb, const float* __restrict__ w_ada,
    const float* __restrict__ b_ada, float* __restrict__ mod)
{
  __shared__ float st[D_];
  int blk = blockIdx.x, tid = threadIdx.x;
  if (blk < 6144){
    const float* s; u16* d; size_t i;
    if      (blk < 1536){ s = w_qkv;  d = wqkvb;  i = ((size_t)blk*256 + tid)*8; }
    else if (blk < 2048){ s = w_proj; d = wprojb; i = ((size_t)(blk-1536)*256 + tid)*8; }
    else if (blk < 4096){ s = w_fc1;  d = wfc1b;  i = ((size_t)(blk-2048)*256 + tid)*8; }
    else                { s = w_fc2;  d = wfc2b;  i = ((size_t)(blk-4096)*256 + tid)*8; }
    float4 a = *(const float4*)(s+i), b = *(const float4*)(s+i+4);
    u16 o[8] = {f2b(a.x),f2b(a.y),f2b(a.z),f2b(a.w),f2b(b.x),f2b(b.y),f2b(b.z),f2b(b.w)};
    *(uint4*)(d+i) = *(const uint4*)o;
    return;
  }
  int idx = blk - 6144;
  int b = idx / 24, jblk = idx % 24;
  for (int i = tid; i < D_; i += 256){
    float x = t_emb[b*D_ + i];
    st[i] = x / (1.f + __expf(-x));
  }
  __syncthreads();
  int j = jblk*256 + tid;
  const float* wr = w_ada + (size_t)j * D_;
  float acc = b_ada[j];
  for (int k = 0; k < D_; k += 8){
    float4 p0 = *(const float4*)(wr + k);
    float4 p1 = *(const float4*)(wr + k + 4);
    acc += p0.x*st[k+0] + p0.y*st[k+1] + p0.z*st[k+2] + p0.w*st[k+3];
    acc += p1.x*st[k+4] + p1.y*st[k+5] + p1.z*st[k+6] + p1.w*st[k+7];
  }
  mod[b*6*D_ + j] = acc;
}

// ---------------- rel-pos bias MLP -> bf16 bias[b,h,n,m]
__global__ __launch_bounds__(256) void k_bias(const float* __restrict__ rel,
    const int* __restrict__ amask,
    const float* __restrict__ w_rp1, const float* __restrict__ b_rp1,
    const float* __restrict__ w_rp2, const float* __restrict__ b_rp2,
    u16* __restrict__ biasbuf)
{
  __shared__ __align__(16) u16 Hs[256*72];
  __shared__ __align__(16) u16 Bs[16*272];
  __shared__ __align__(16) u16 w2s[16*72];
  __shared__ float b2s[16];
  __shared__ u16 msk[256];
  int mh = blockIdx.x, n = blockIdx.y, b = blockIdx.z;
  int tid = threadIdx.x;
  int w = tid >> 6, lane = tid & 63, ln = lane & 15, quad = lane >> 4;

  for (int i = tid; i < 1024; i += 256) w2s[(i>>6)*72 + (i&63)] = f2b(w_rp2[i]);
  if (tid < 16) b2s[tid] = b_rp2[tid];
  msk[tid] = (u16)(amask[b*N_ + mh*256 + tid] != 0);

  {
    float2 r01 = *(const float2*)(rel + ((size_t)((b*N_ + n)*N_) + mh*256 + tid)*2);
    u16 hv[64];
    #pragma unroll
    for (int j=0;j<64;j++){
      float t = w_rp1[2*j]*r01.x + w_rp1[2*j+1]*r01.y + b_rp1[j];
      hv[j] = f2b(t > 0.f ? t : 0.f);
    }
    uint4* dst = (uint4*)&Hs[tid*72];
    #pragma unroll
    for (int c=0;c<8;c++) dst[c] = *(const uint4*)&hv[c*8];
  }
  __syncthreads();

  bf16x8 af0 = *(const bf16x8*)&w2s[ln*72 + quad*8];
  bf16x8 af1 = *(const bf16x8*)&w2s[ln*72 + 32 + quad*8];

  #pragma unroll
  for (int t=0; t<4; t++){
    int mt = w*4 + t;
    bf16x8 bf0 = *(const bf16x8*)&Hs[(mt*16+ln)*72 + quad*8];
    bf16x8 bf1 = *(const bf16x8*)&Hs[(mt*16+ln)*72 + 32 + quad*8];
    f32x4 c = {};
    c = __builtin_amdgcn_mfma_f32_16x16x32_bf16(af0, bf0, c, 0,0,0);
    c = __builtin_amdgcn_mfma_f32_16x16x32_bf16(af1, bf1, c, 0,0,0);
    bool valid = msk[mt*16 + ln] != 0;
    #pragma unroll
    for (int i=0;i<4;i++){
      int h = quad*4 + i;
      float val = valid ? (c[i] + b2s[h]) : -1e30f;
      Bs[h*272 + mt*16 + ln] = f2b(val);
    }
  }
  __syncthreads();

  #pragma unroll
  for (int it=0; it<8; it++){
    int idx = it*256 + tid;
    int r = idx >> 7, cc = idx & 127;
    size_t rb = (((size_t)(b*H_ + r)*N_) + n)*N_ + mh*256;
    ((unsigned int*)(biasbuf + rb))[cc] = ((const unsigned int*)(Bs + r*272))[cc];
  }
}

// ---------------- LayerNorm + adaLN modulate -> bf16 (LN1)
__global__ __launch_bounds__(256) void k_lnmod(const float* __restrict__ xin,
    const float* __restrict__ g, const float* __restrict__ be,
    const float* __restrict__ mod, int shift_idx, int scale_idx,
    u16* __restrict__ xn)
{
  int row = blockIdx.x;
  int b = row >> 9;
  float v[4]; float s = 0.f, s2 = 0.f;
  #pragma unroll
  for (int i=0;i<4;i++){
    float x = xin[(size_t)row*D_ + threadIdx.x + i*256];
    v[i] = x; s += x; s2 += x*x;
  }
  #pragma unroll
  for (int o=32;o>0;o>>=1){ s += __shfl_down(s,o); s2 += __shfl_down(s2,o); }
  __shared__ float rs[4], rs2[4];
  int w = threadIdx.x >> 6;
  if ((threadIdx.x & 63)==0){ rs[w]=s; rs2[w]=s2; }
  __syncthreads();
  s = rs[0]+rs[1]+rs[2]+rs[3]; s2 = rs2[0]+rs2[1]+rs2[2]+rs2[3];
  float mu = s * (1.f/D_);
  float var = s2 * (1.f/D_) - mu*mu;
  float rstd = rsqrtf(var + 1e-5f);
  const float* mrow = mod + b*6*D_;
  #pragma unroll
  for (int i=0;i<4;i++){
    int d = threadIdx.x + i*256;
    float xg = (v[i]-mu)*rstd*g[d] + be[d];
    xn[(size_t)row*D_ + d] = f2b(xg * (1.f + mrow[scale_idx*D_ + d]) + mrow[shift_idx*D_ + d]);
  }
}

// ---------------- 64x128-tile MFMA GEMM, BK=64, XOR-swizzle, direct epilogue.
enum { EPI_PLAIN=0, EPI_GELU=1 };

template<int EPI>
__global__ __launch_bounds__(256) void k_gemm64(const u16* __restrict__ A,
    const u16* __restrict__ W, const float* __restrict__ Wb, int K, int ldc,
    u16* __restrict__ o_u16)
{
  __shared__ __align__(16) u16 Al[64*64];
  __shared__ __align__(16) u16 Wl[128*64];
  int row0 = blockIdx.y*64, col0 = blockIdx.x*128;
  int tid = threadIdx.x;
  int w = tid >> 6, lane = tid & 63, ln = lane & 15, quad = lane >> 4;
  int wy = w >> 1, wx = w & 1;
  int srow = tid >> 3;
  int schunk = (tid & 7) ^ (srow & 7);
  const u16* Ag = A + (size_t)(row0 + srow)*K + schunk*8;
  const u16* Wg = W + (size_t)(col0 + srow)*K + schunk*8;
  int aoff[2][2], woff[4][2];
  #pragma unroll
  for (int ms=0; ms<2; ms++){
    int r = 32*wy + 16*ms + ln;
    #pragma unroll
    for (int kk=0; kk<2; kk++)
      aoff[ms][kk] = r*64 + (((kk*4+quad) ^ (ln&7))*8);
  }
  #pragma unroll
  for (int ns=0; ns<4; ns++){
    int r = 64*wx + 16*ns + ln;
    #pragma unroll
    for (int kk=0; kk<2; kk++)
      woff[ns][kk] = r*64 + (((kk*4+quad) ^ (ln&7))*8);
  }
  f32x4 acc[2][4] = {};
  for (int k0 = 0; k0 < K; k0 += 64){
    gload16(Ag + k0,                  Al + tid*8);
    gload16(Ag + k0 + (size_t)32*K,   Al + 2048 + tid*8);
    #pragma unroll
    for (int i=0;i<4;i++)
      gload16(Wg + k0 + (size_t)(32*i)*K, Wl + i*2048 + tid*8);
    __syncthreads();
    #pragma unroll
    for (int kk=0; kk<2; kk++){
      bf16x8 af[2], bfr[4];
      #pragma unroll
      for (int ms=0; ms<2; ms++) af[ms]  = *(const bf16x8*)&Al[aoff[ms][kk]];
      #pragma unroll
      for (int ns=0; ns<4; ns++) bfr[ns] = *(const bf16x8*)&Wl[woff[ns][kk]];
      #pragma unroll
      for (int ms=0; ms<2; ms++)
        #pragma unroll
        for (int ns=0; ns<4; ns++)
          acc[ms][ns] = __builtin_amdgcn_mfma_f32_16x16x32_bf16(af[ms], bfr[ns], acc[ms][ns], 0,0,0);
    }
    __syncthreads();
  }
  #pragma unroll
  for (int ms=0; ms<2; ms++){
    #pragma unroll
    for (int ns=0; ns<4; ns++){
      int c = col0 + 64*wx + 16*ns + ln;
      float wb = Wb[c];
      #pragma unroll
      for (int i=0;i<4;i++){
        int r = row0 + 32*wy + 16*ms + quad*4 + i;
        float val = acc[ms][ns][i] + wb;
        if (EPI == EPI_GELU) val = 0.5f*val*(1.f + erff(val*0.70710678f));
        o_u16[(size_t)r*ldc + c] = f2b(val);
      }
    }
  }
}

// ---------------- 128x128-tile split-K GEMM -> bf16 partials (4 slices)
__global__ __launch_bounds__(256) void k_gemm(const u16* __restrict__ A,
    const u16* __restrict__ W, int K, int Kslice, int ldc,
    u16* __restrict__ part)
{
  __shared__ __align__(16) u16 Al[128*64];
  __shared__ __align__(16) u16 Wl[128*64];
  int row0 = blockIdx.y*128, col0 = blockIdx.x*128;
  int tid = threadIdx.x;
  int w = tid >> 6, lane = tid & 63, ln = lane & 15, quad = lane >> 4;
  int wy = w >> 1, wx = w & 1;
  int srow = tid >> 3;
  int schunk = (tid & 7) ^ (srow & 7);
  const u16* Ag = A + (size_t)(row0 + srow)*K + schunk*8;
  const u16* Wg = W + (size_t)(col0 + srow)*K + schunk*8;
  int aoff[4][2], woff[4][2];
  #pragma unroll
  for (int ms=0; ms<4; ms++){
    int r = 64*wy + 16*ms + ln;
    #pragma unroll
    for (int kk=0; kk<2; kk++)
      aoff[ms][kk] = r*64 + (((kk*4+quad) ^ (ln&7))*8);
  }
  #pragma unroll
  for (int ns=0; ns<4; ns++){
    int r = 64*wx + 16*ns + ln;
    #pragma unroll
    for (int kk=0; kk<2; kk++)
      woff[ns][kk] = r*64 + (((kk*4+quad) ^ (ln&7))*8);
  }
  f32x4 acc[4][4] = {};
  int kbeg = blockIdx.z * Kslice;
  for (int k0 = kbeg; k0 < kbeg + Kslice; k0 += 64){
    #pragma unroll
    for (int i=0;i<4;i++){
      gload16(Ag + k0 + (size_t)(32*i)*K, Al + i*2048 + tid*8);
      gload16(Wg + k0 + (size_t)(32*i)*K, Wl + i*2048 + tid*8);
    }
    __syncthreads();
    #pragma unroll
    for (int kk=0; kk<2; kk++){
      bf16x8 af[4], bfr[4];
      #pragma unroll
      for (int ms=0; ms<4; ms++) af[ms]  = *(const bf16x8*)&Al[aoff[ms][kk]];
      #pragma unroll
      for (int ns=0; ns<4; ns++) bfr[ns] = *(const bf16x8*)&Wl[woff[ns][kk]];
      #pragma unroll
      for (int ms=0; ms<4; ms++)
        #pragma unroll
        for (int ns=0; ns<4; ns++)
          acc[ms][ns] = __builtin_amdgcn_mfma_f32_16x16x32_bf16(af[ms], bfr[ns], acc[ms][ns], 0,0,0);
    }
    __syncthreads();
  }
  u16* pbase = part + (size_t)blockIdx.z*M_*ldc;
  #pragma unroll
  for (int ms=0; ms<4; ms++){
    #pragma unroll
    for (int ns=0; ns<4; ns++){
      int c = col0 + 64*wx + 16*ns + ln;
      #pragma unroll
      for (int i=0;i<4;i++){
        int r = row0 + 64*wy + 16*ms + quad*4 + i;
        pbase[(size_t)r*ldc + c] = f2b(acc[ms][ns][i]);
      }
    }
  }
}

// ---------------- 4-slice reduce + bias + gate + residual -> f32 out
template<int GIDX>
__global__ __launch_bounds__(256) void k_red4(const u16* __restrict__ part,
    const float* __restrict__ Wb, const float* __restrict__ mod,
    const float* __restrict__ resid, float* __restrict__ outp)
{
  size_t i = ((size_t)blockIdx.x*256 + threadIdx.x)*4;
  int c = (int)(i & 1023); int r = (int)(i >> 10); int b = r >> 9;
  uint2 a0 = *(const uint2*)(part + i);
  uint2 a1 = *(const uint2*)(part + (size_t)M_*D_ + i);
  uint2 a2 = *(const uint2*)(part + (size_t)2*M_*D_ + i);
  uint2 a3 = *(const uint2*)(part + (size_t)3*M_*D_ + i);
  float4 pv;
  pv.x = b2f((u16)(a0.x&0xffff)) + b2f((u16)(a1.x&0xffff)) + b2f((u16)(a2.x&0xffff)) + b2f((u16)(a3.x&0xffff));
  pv.y = b2f((u16)(a0.x>>16))    + b2f((u16)(a1.x>>16))    + b2f((u16)(a2.x>>16))    + b2f((u16)(a3.x>>16));
  pv.z = b2f((u16)(a0.y&0xffff)) + b2f((u16)(a1.y&0xffff)) + b2f((u16)(a2.y&0xffff)) + b2f((u16)(a3.y&0xffff));
  pv.w = b2f((u16)(a0.y>>16))    + b2f((u16)(a1.y>>16))    + b2f((u16)(a2.y>>16))    + b2f((u16)(a3.y>>16));
  float4 x4 = *(const float4*)(resid + i);
  float4 bi = *(const float4*)(Wb + c);
  float4 g4 = *(const float4*)(mod + b*6*D_ + GIDX*D_ + c);
  float4 o;
  o.x = x4.x + g4.x*(pv.x + bi.x);
  o.y = x4.y + g4.y*(pv.y + bi.y);
  o.z = x4.z + g4.z*(pv.z + bi.z);
  o.w = x4.w + g4.w*(pv.w + bi.w);
  *(float4*)(outp + i) = o;
}

// ---------------- PROJ 4-slice reduce + gate_s + residual -> xm, LN2+mod -> xn
__global__ __launch_bounds__(256) void k_redln(const u16* __restrict__ part,
    const float* __restrict__ Wb, const float* __restrict__ mod,
    const float* __restrict__ resid, const float* __restrict__ g,
    const float* __restrict__ be, float* __restrict__ xm, u16* __restrict__ xn)
{
  int row = blockIdx.x, b = row >> 9, tid = threadIdx.x;
  size_t i = (size_t)row*D_ + tid*4;
  int c = tid*4;
  uint2 a0 = *(const uint2*)(part + i);
  uint2 a1 = *(const uint2*)(part + (size_t)M_*D_ + i);
  uint2 a2 = *(const uint2*)(part + (size_t)2*M_*D_ + i);
  uint2 a3 = *(const uint2*)(part + (size_t)3*M_*D_ + i);
  float4 pv;
  pv.x = b2f((u16)(a0.x&0xffff)) + b2f((u16)(a1.x&0xffff)) + b2f((u16)(a2.x&0xffff)) + b2f((u16)(a3.x&0xffff));
  pv.y = b2f((u16)(a0.x>>16))    + b2f((u16)(a1.x>>16))    + b2f((u16)(a2.x>>16))    + b2f((u16)(a3.x>>16));
  pv.z = b2f((u16)(a0.y&0xffff)) + b2f((u16)(a1.y&0xffff)) + b2f((u16)(a2.y&0xffff)) + b2f((u16)(a3.y&0xffff));
  pv.w = b2f((u16)(a0.y>>16))    + b2f((u16)(a1.y>>16))    + b2f((u16)(a2.y>>16))    + b2f((u16)(a3.y>>16));
  float4 x4 = *(const float4*)(resid + i);
  float4 bi = *(const float4*)(Wb + c);
  float4 g4 = *(const float4*)(mod + b*6*D_ + 2*D_ + c);
  float4 mid;
  mid.x = x4.x + g4.x*(pv.x + bi.x);
  mid.y = x4.y + g4.y*(pv.y + bi.y);
  mid.z = x4.z + g4.z*(pv.z + bi.z);
  mid.w = x4.w + g4.w*(pv.w + bi.w);
  *(float4*)(xm + i) = mid;
  float s = mid.x+mid.y+mid.z+mid.w;
  float s2 = mid.x*mid.x+mid.y*mid.y+mid.z*mid.z+mid.w*mid.w;
  #pragma unroll
  for (int o=32;o>0;o>>=1){ s += __shfl_down(s,o); s2 += __shfl_down(s2,o); }
  __shared__ float rs[4], rs2[4];
  int w = tid >> 6;
  if ((tid & 63)==0){ rs[w]=s; rs2[w]=s2; }
  __syncthreads();
  s = rs[0]+rs[1]+rs[2]+rs[3]; s2 = rs2[0]+rs2[1]+rs2[2]+rs2[3];
  float mu = s * (1.f/D_);
  float var = s2 * (1.f/D_) - mu*mu;
  float rstd = rsqrtf(var + 1e-5f);
  const float* mrow = mod + b*6*D_;
  float4 gg = *(const float4*)(g + c);
  float4 bb = *(const float4*)(be + c);
  float4 sc = *(const float4*)(mrow + 4*D_ + c);
  float4 sh = *(const float4*)(mrow + 3*D_ + c);
  u16 o[4];
  o[0] = f2b(((mid.x-mu)*rstd*gg.x + bb.x)*(1.f+sc.x) + sh.x);
  o[1] = f2b(((mid.y-mu)*rstd*gg.y + bb.y)*(1.f+sc.y) + sh.y);
  o[2] = f2b(((mid.z-mu)*rstd*gg.z + bb.z)*(1.f+sc.z) + sh.z);
  o[3] = f2b(((mid.w-mu)*rstd*gg.w + bb.w)*(1.f+sc.w) + sh.w);
  *(uint2*)(xn + i) = *(const uint2*)o;
}

// ---------------- flash attention: block = (nt64, h, b), 4 waves, 64 q-rows
__global__ __launch_bounds__(256) void k_attn(const u16* __restrict__ qkv,
    const u16* __restrict__ biasbuf, u16* __restrict__ attn_out)
{
  __shared__ __align__(16) u16 Qs[64*72];
  __shared__ __align__(16) u16 Ks[64*72];
  __shared__ __align__(16) u16 Vt[64*72];
  __shared__ __align__(16) u16 Ps[4*16*72];
  int nt = blockIdx.x, h = blockIdx.y, b = blockIdx.z;
  int n0 = nt*64;
  int tid = threadIdx.x;
  int w = tid >> 6, lane = tid & 63, ln = lane & 15, quad = lane >> 4;

  {
    int row = tid >> 2, cb = (tid & 3)*16;
    const u16* src = qkv + (size_t)(b*N_ + n0 + row)*3072 + h*64 + cb;
    uint4 q0 = *(const uint4*)src, q1 = *(const uint4*)(src+8);
    uint4* dst = (uint4*)&Qs[row*72 + cb];
    dst[0] = q0; dst[1] = q1;
  }
  __syncthreads();
  bf16x8 qf[2];
  qf[0] = *(const bf16x8*)&Qs[(16*w+ln)*72 + quad*8];
  qf[1] = *(const bf16x8*)&Qs[(16*w+ln)*72 + 32 + quad*8];

  f32x4 oacc[4] = {};
  float rmax[4] = {-3e38f,-3e38f,-3e38f,-3e38f};
  float rsum[4] = {0.f,0.f,0.f,0.f};
  const u16* bp = biasbuf + (((size_t)(b*H_ + h)*N_) + n0 + 16*w)*N_ + ln;

  for (int mt = 0; mt < 8; mt++){
    __syncthreads();
    {
      int r = tid >> 2, cb = (tid & 3)*16;
      const u16* kp = qkv + (size_t)(b*N_ + mt*64 + r)*3072 + 1024 + h*64 + cb;
      uint4 k0 = *(const uint4*)kp, k1 = *(const uint4*)(kp+8);
      uint4* kd = (uint4*)&Ks[r*72 + cb];
      kd[0] = k0; kd[1] = k1;
      const u16* vp = qkv + (size_t)(b*N_ + mt*64 + r)*3072 + 2048 + h*64 + cb;
      uint4 v0 = *(const uint4*)vp, v1 = *(const uint4*)(vp+8);
      u16 ve[16];
      *(uint4*)&ve[0] = v0; *(uint4*)&ve[8] = v1;
      #pragma unroll
      for (int j=0;j<16;j++) Vt[(cb+j)*72 + r] = ve[j];
    }
    __syncthreads();

    u16 bl[4][4];
    #pragma unroll
    for (int cs=0; cs<4; cs++)
      #pragma unroll
      for (int i=0;i<4;i++)
        bl[cs][i] = bp[(size_t)(quad*4+i)*N_ + mt*64 + 16*cs];

    f32x4 s[4];
    #pragma unroll
    for (int cs=0; cs<4; cs++){
      bf16x8 k0f = *(const bf16x8*)&Ks[(16*cs+ln)*72 + quad*8];
      bf16x8 k1f = *(const bf16x8*)&Ks[(16*cs+ln)*72 + 32 + quad*8];
      f32x4 z = {};
      z = __builtin_amdgcn_mfma_f32_16x16x32_bf16(qf[0], k0f, z, 0,0,0);
      z = __builtin_amdgcn_mfma_f32_16x16x32_bf16(qf[1], k1f, z, 0,0,0);
      s[cs] = z;
    }
    #pragma unroll
    for (int cs=0; cs<4; cs++)
      #pragma unroll
      for (int i=0;i<4;i++)
        s[cs][i] = s[cs][i]*0.125f + b2f(bl[cs][i]);

    #pragma unroll
    for (int i=0;i<4;i++){
      float tm = fmaxf(fmaxf(s[0][i], s[1][i]), fmaxf(s[2][i], s[3][i]));
      #pragma unroll
      for (int o=1;o<16;o<<=1) tm = fmaxf(tm, __shfl_xor(tm, o));
      float nm = fmaxf(rmax[i], tm);
      float alpha = __expf(rmax[i] - nm);
      rmax[i] = nm;
      float ps = 0.f;
      #pragma unroll
      for (int cs=0; cs<4; cs++){
        float p = __expf(s[cs][i] - nm);
        s[cs][i] = p; ps += p;
      }
      #pragma unroll
      for (int o=1;o<16;o<<=1) ps += __shfl_xor(ps, o);
      rsum[i] = rsum[i]*alpha + ps;
      #pragma unroll
      for (int ds=0; ds<4; ds++) oacc[ds][i] *= alpha;
    }

    #pragma unroll
    for (int cs=0; cs<4; cs++)
      #pragma unroll
      for (int i=0;i<4;i++)
        Ps[w*1152 + (quad*4+i)*72 + 16*cs + ln] = f2b(s[cs][i]);

    bf16x8 pf0 = *(const bf16x8*)&Ps[w*1152 + ln*72 + quad*8];
    bf16x8 pf1 = *(const bf16x8*)&Ps[w*1152 + ln*72 + 32 + quad*8];
    #pragma unroll
    for (int ds=0; ds<4; ds++){
      bf16x8 v0f = *(const bf16x8*)&Vt[(16*ds+ln)*72 + quad*8];
      bf16x8 v1f = *(const bf16x8*)&Vt[(16*ds+ln)*72 + 32 + quad*8];
      oacc[ds] = __builtin_amdgcn_mfma_f32_16x16x32_bf16(pf0, v0f, oacc[ds], 0,0,0);
      oacc[ds] = __builtin_amdgcn_mfma_f32_16x16x32_bf16(pf1, v1f, oacc[ds], 0,0,0);
    }
  }

  #pragma unroll
  for (int i=0;i<4;i++){
    float inv = 1.f / rsum[i];
    int r = b*N_ + n0 + 16*w + quad*4 + i;
    #pragma unroll
    for (int ds=0; ds<4; ds++)
      attn_out[(size_t)r*D_ + h*64 + 16*ds + ln] = f2b(oacc[ds][i]*inv);
  }
}

extern "C" void kernel_launch(void* const* d_in, const int* in_sizes, int n_in,
                              void* d_out, int out_size, void* d_ws, size_t ws_size,
                              hipStream_t stream) {
  const float* x      = (const float*)d_in[0];
  const float* t_emb  = (const float*)d_in[1];
  const float* rel    = (const float*)d_in[2];
  const int*   amask  = (const int*)d_in[3];
  const float* w_ada  = (const float*)d_in[4];
  const float* b_ada  = (const float*)d_in[5];
  const float* g1     = (const float*)d_in[6];
  const float* beta1  = (const float*)d_in[7];
  const float* g2     = (const float*)d_in[8];
  const float* beta2  = (const float*)d_in[9];
  const float* w_qkv  = (const float*)d_in[10];
  const float* b_qkv  = (const float*)d_in[11];
  const float* w_proj = (const float*)d_in[12];
  const float* b_proj = (const float*)d_in[13];
  const float* w_rp1  = (const float*)d_in[14];
  const float* b_rp1  = (const float*)d_in[15];
  const float* w_rp2  = (const float*)d_in[16];
  const float* b_rp2  = (const float*)d_in[17];
  const float* w_fc1  = (const float*)d_in[18];
  const float* b_fc1  = (const float*)d_in[19];
  const float* w_fc2  = (const float*)d_in[20];
  const float* b_fc2  = (const float*)d_in[21];
  float* outp = (float*)d_out;

  const size_t MB = 1u<<20;
  char* wsb = (char*)d_ws;
  float* mod   = (float*)(wsb);
  u16*  xn     = (u16*) (wsb + 131072);
  float* xm    = (float*)(wsb + 131072 + 4*MB);
  u16*  wqkvb  = (u16*) (wsb + 131072 + 12*MB);
  u16*  wprojb = (u16*) (wsb + 131072 + 18*MB);
  u16*  wfc1b  = (u16*) (wsb + 131072 + 20*MB);
  u16*  wfc2b  = (u16*) (wsb + 131072 + 28*MB);
  u16*  qkvb   = (u16*) (wsb + 131072 + 36*MB);
  u16*  biasb  = (u16*) (wsb + 131072 + 48*MB);
  u16*  hb     = (u16*) (wsb + 131072 + 80*MB);
  u16*  parts  = (u16*) (wsb + 131072 + 96*MB);

  // 1) converts + adaLN mod (low-LDS streaming launch)
  k_cvtmod<<<6240, 256, 0, stream>>>(
      w_qkv, wqkvb, w_proj, wprojb, w_fc1, wfc1b, w_fc2, wfc2b,
      t_emb, w_ada, b_ada, mod);
  // 2) rel-pos bias (heavy-LDS launch)
  k_bias<<<dim3(2, N_, B_), 256, 0, stream>>>(rel, amask, w_rp1, b_rp1, w_rp2, b_rp2, biasb);
  // 3) LN1
  k_lnmod<<<M_, 256, 0, stream>>>(x, g1, beta1, mod, 0, 1, xn);
  // 4) QKV 64x128 direct
  k_gemm64<EPI_PLAIN><<<dim3(3072/128, M_/64), 256, 0, stream>>>(
      xn, wqkvb, b_qkv, D_, 3072, qkvb);
  // 5) attention
  k_attn<<<dim3(8, H_, B_), 256, 0, stream>>>(qkvb, biasb, xn);
  // 6) PROJ split-K x4
  k_gemm<<<dim3(D_/128, M_/128, 4), 256, 0, stream>>>(
      xn, wprojb, D_, D_/4, D_, parts);
  // 7) PROJ reduce + LN2
  k_redln<<<M_, 256, 0, stream>>>(parts, b_proj, mod, x, g2, beta2, xm, xn);
  // 8) FC1 64x128 + GELU
  k_gemm64<EPI_GELU><<<dim3(HID_/128, M_/64), 256, 0, stream>>>(
      xn, wfc1b, b_fc1, D_, HID_, hb);
  // 9) FC2 split-K x4
  k_gemm<<<dim3(D_/128, M_/128, 4), 256, 0, stream>>>(
      hb, wfc2b, HID_, HID_/4, D_, parts);
  // 10) FC2 reduce -> out
  k_red4<5><<<2048, 256, 0, stream>>>(parts, b_fc2, mod, xm, outp);
}

// Round 11
// 354.118 us; speedup vs baseline: 1.0932x; 1.0932x over previous
//
#include <hip/hip_runtime.h>

// DiT block, B=4 N=512 D=1024 H=16 HD=64 HID=4096 RP_HID=64. All f32 I/O.
// R11: k_cvtmod rewritten for MLP (4 independent 32B loads in flight/thread,
//      8192 floats/block). R10 showed converts are latency-bound (612 GB/s,
//      VALU 1.8%), not LDS/occupancy-bound. Rest identical to R10.
// ws (byte off): mod@0(128K) | xn@128K(4M) | xm@+4M(8M) | wqkvb@+12M(6M) |
//   wprojb@+18M(2M) | wfc1b@+20M(8M) | wfc2b@+28M(8M) | qkvb@+36M(12M) |
//   biasb@+48M(32M) | hb@+80M(16M) | parts@+96M(16M)

#define B_ 4
#define N_ 512
#define D_ 1024
#define H_ 16
#define HID_ 4096
#define M_ (B_*N_)

typedef unsigned short u16;
typedef __attribute__((ext_vector_type(8))) short bf16x8;
typedef __attribute__((ext_vector_type(4))) float f32x4;

__device__ __forceinline__ float b2f(u16 u){
  union { unsigned int i; float f; } x; x.i = ((unsigned int)u) << 16; return x.f;
}
__device__ __forceinline__ u16 f2b(float f){          // RNE
  unsigned int u = __float_as_uint(f);
  return (u16)((u + 0x7fffu + ((u >> 16) & 1u)) >> 16);
}

__device__ __forceinline__ void gload16(const u16* __restrict__ g, u16* l){
#if defined(__has_builtin) && __has_builtin(__builtin_amdgcn_global_load_lds)
  __builtin_amdgcn_global_load_lds(
      (const __attribute__((address_space(1))) unsigned int*)g,
      (__attribute__((address_space(3))) unsigned int*)l, 16, 0, 0);
#else
  *(uint4*)l = *(const uint4*)g;
#endif
}

// ---------------- converts (high-MLP, 8192 floats/block) + adaLN mod
// [0,384) w_qkv | [384,512) w_proj | [512,1024) w_fc1 | [1024,1536) w_fc2
// [1536,1632) mod (24 jblk x 4 b)
__global__ __launch_bounds__(256) void k_cvtmod(
    const float* __restrict__ w_qkv, u16* __restrict__ wqkvb,
    const float* __restrict__ w_proj, u16* __restrict__ wprojb,
    const float* __restrict__ w_fc1, u16* __restrict__ wfc1b,
    const float* __restrict__ w_fc2, u16* __restrict__ wfc2b,
    const float* __restrict__ t_emb, const float* __restrict__ w_ada,
    const float* __restrict__ b_ada, float* __restrict__ mod)
{
  __shared__ float st[D_];
  int blk = blockIdx.x, tid = threadIdx.x;
  if (blk < 1536){
    const float* s; u16* d; size_t base;
    if      (blk <  384){ s = w_qkv;  d = wqkvb;  base = (size_t)blk*8192; }
    else if (blk <  512){ s = w_proj; d = wprojb; base = (size_t)(blk-384)*8192; }
    else if (blk < 1024){ s = w_fc1;  d = wfc1b;  base = (size_t)(blk-512)*8192; }
    else                { s = w_fc2;  d = wfc2b;  base = (size_t)(blk-1024)*8192; }
    // 4 independent 32B loads in flight per thread
    float4 a[4], b[4];
    #pragma unroll
    for (int it=0; it<4; it++){
      size_t i = base + (size_t)it*2048 + (size_t)tid*8;
      a[it] = *(const float4*)(s+i);
      b[it] = *(const float4*)(s+i+4);
    }
    #pragma unroll
    for (int it=0; it<4; it++){
      size_t i = base + (size_t)it*2048 + (size_t)tid*8;
      u16 o[8] = {f2b(a[it].x),f2b(a[it].y),f2b(a[it].z),f2b(a[it].w),
                  f2b(b[it].x),f2b(b[it].y),f2b(b[it].z),f2b(b[it].w)};
      *(uint4*)(d+i) = *(const uint4*)o;
    }
    return;
  }
  int idx = blk - 1536;
  int b = idx / 24, jblk = idx % 24;
  for (int i = tid; i < D_; i += 256){
    float x = t_emb[b*D_ + i];
    st[i] = x / (1.f + __expf(-x));
  }
  __syncthreads();
  int j = jblk*256 + tid;
  const float* wr = w_ada + (size_t)j * D_;
  float acc = b_ada[j];
  for (int k = 0; k < D_; k += 8){
    float4 p0 = *(const float4*)(wr + k);
    float4 p1 = *(const float4*)(wr + k + 4);
    acc += p0.x*st[k+0] + p0.y*st[k+1] + p0.z*st[k+2] + p0.w*st[k+3];
    acc += p1.x*st[k+4] + p1.y*st[k+5] + p1.z*st[k+6] + p1.w*st[k+7];
  }
  mod[b*6*D_ + j] = acc;
}

// ---------------- rel-pos bias MLP -> bf16 bias[b,h,n,m]
__global__ __launch_bounds__(256) void k_bias(const float* __restrict__ rel,
    const int* __restrict__ amask,
    const float* __restrict__ w_rp1, const float* __restrict__ b_rp1,
    const float* __restrict__ w_rp2, const float* __restrict__ b_rp2,
    u16* __restrict__ biasbuf)
{
  __shared__ __align__(16) u16 Hs[256*72];
  __shared__ __align__(16) u16 Bs[16*272];
  __shared__ __align__(16) u16 w2s[16*72];
  __shared__ float b2s[16];
  __shared__ u16 msk[256];
  int mh = blockIdx.x, n = blockIdx.y, b = blockIdx.z;
  int tid = threadIdx.x;
  int w = tid >> 6, lane = tid & 63, ln = lane & 15, quad = lane >> 4;

  for (int i = tid; i < 1024; i += 256) w2s[(i>>6)*72 + (i&63)] = f2b(w_rp2[i]);
  if (tid < 16) b2s[tid] = b_rp2[tid];
  msk[tid] = (u16)(amask[b*N_ + mh*256 + tid] != 0);

  {
    float2 r01 = *(const float2*)(rel + ((size_t)((b*N_ + n)*N_) + mh*256 + tid)*2);
    u16 hv[64];
    #pragma unroll
    for (int j=0;j<64;j++){
      float t = w_rp1[2*j]*r01.x + w_rp1[2*j+1]*r01.y + b_rp1[j];
      hv[j] = f2b(t > 0.f ? t : 0.f);
    }
    uint4* dst = (uint4*)&Hs[tid*72];
    #pragma unroll
    for (int c=0;c<8;c++) dst[c] = *(const uint4*)&hv[c*8];
  }
  __syncthreads();

  bf16x8 af0 = *(const bf16x8*)&w2s[ln*72 + quad*8];
  bf16x8 af1 = *(const bf16x8*)&w2s[ln*72 + 32 + quad*8];

  #pragma unroll
  for (int t=0; t<4; t++){
    int mt = w*4 + t;
    bf16x8 bf0 = *(const bf16x8*)&Hs[(mt*16+ln)*72 + quad*8];
    bf16x8 bf1 = *(const bf16x8*)&Hs[(mt*16+ln)*72 + 32 + quad*8];
    f32x4 c = {};
    c = __builtin_amdgcn_mfma_f32_16x16x32_bf16(af0, bf0, c, 0,0,0);
    c = __builtin_amdgcn_mfma_f32_16x16x32_bf16(af1, bf1, c, 0,0,0);
    bool valid = msk[mt*16 + ln] != 0;
    #pragma unroll
    for (int i=0;i<4;i++){
      int h = quad*4 + i;
      float val = valid ? (c[i] + b2s[h]) : -1e30f;
      Bs[h*272 + mt*16 + ln] = f2b(val);
    }
  }
  __syncthreads();

  #pragma unroll
  for (int it=0; it<8; it++){
    int idx = it*256 + tid;
    int r = idx >> 7, cc = idx & 127;
    size_t rb = (((size_t)(b*H_ + r)*N_) + n)*N_ + mh*256;
    ((unsigned int*)(biasbuf + rb))[cc] = ((const unsigned int*)(Bs + r*272))[cc];
  }
}

// ---------------- LayerNorm + adaLN modulate -> bf16 (LN1)
__global__ __launch_bounds__(256) void k_lnmod(const float* __restrict__ xin,
    const float* __restrict__ g, const float* __restrict__ be,
    const float* __restrict__ mod, int shift_idx, int scale_idx,
    u16* __restrict__ xn)
{
  int row = blockIdx.x;
  int b = row >> 9;
  float v[4]; float s = 0.f, s2 = 0.f;
  #pragma unroll
  for (int i=0;i<4;i++){
    float x = xin[(size_t)row*D_ + threadIdx.x + i*256];
    v[i] = x; s += x; s2 += x*x;
  }
  #pragma unroll
  for (int o=32;o>0;o>>=1){ s += __shfl_down(s,o); s2 += __shfl_down(s2,o); }
  __shared__ float rs[4], rs2[4];
  int w = threadIdx.x >> 6;
  if ((threadIdx.x & 63)==0){ rs[w]=s; rs2[w]=s2; }
  __syncthreads();
  s = rs[0]+rs[1]+rs[2]+rs[3]; s2 = rs2[0]+rs2[1]+rs2[2]+rs2[3];
  float mu = s * (1.f/D_);
  float var = s2 * (1.f/D_) - mu*mu;
  float rstd = rsqrtf(var + 1e-5f);
  const float* mrow = mod + b*6*D_;
  #pragma unroll
  for (int i=0;i<4;i++){
    int d = threadIdx.x + i*256;
    float xg = (v[i]-mu)*rstd*g[d] + be[d];
    xn[(size_t)row*D_ + d] = f2b(xg * (1.f + mrow[scale_idx*D_ + d]) + mrow[shift_idx*D_ + d]);
  }
}

// ---------------- 64x128-tile MFMA GEMM, BK=64, XOR-swizzle, direct epilogue.
enum { EPI_PLAIN=0, EPI_GELU=1 };

template<int EPI>
__global__ __launch_bounds__(256) void k_gemm64(const u16* __restrict__ A,
    const u16* __restrict__ W, const float* __restrict__ Wb, int K, int ldc,
    u16* __restrict__ o_u16)
{
  __shared__ __align__(16) u16 Al[64*64];
  __shared__ __align__(16) u16 Wl[128*64];
  int row0 = blockIdx.y*64, col0 = blockIdx.x*128;
  int tid = threadIdx.x;
  int w = tid >> 6, lane = tid & 63, ln = lane & 15, quad = lane >> 4;
  int wy = w >> 1, wx = w & 1;
  int srow = tid >> 3;
  int schunk = (tid & 7) ^ (srow & 7);
  const u16* Ag = A + (size_t)(row0 + srow)*K + schunk*8;
  const u16* Wg = W + (size_t)(col0 + srow)*K + schunk*8;
  int aoff[2][2], woff[4][2];
  #pragma unroll
  for (int ms=0; ms<2; ms++){
    int r = 32*wy + 16*ms + ln;
    #pragma unroll
    for (int kk=0; kk<2; kk++)
      aoff[ms][kk] = r*64 + (((kk*4+quad) ^ (ln&7))*8);
  }
  #pragma unroll
  for (int ns=0; ns<4; ns++){
    int r = 64*wx + 16*ns + ln;
    #pragma unroll
    for (int kk=0; kk<2; kk++)
      woff[ns][kk] = r*64 + (((kk*4+quad) ^ (ln&7))*8);
  }
  f32x4 acc[2][4] = {};
  for (int k0 = 0; k0 < K; k0 += 64){
    gload16(Ag + k0,                  Al + tid*8);
    gload16(Ag + k0 + (size_t)32*K,   Al + 2048 + tid*8);
    #pragma unroll
    for (int i=0;i<4;i++)
      gload16(Wg + k0 + (size_t)(32*i)*K, Wl + i*2048 + tid*8);
    __syncthreads();
    #pragma unroll
    for (int kk=0; kk<2; kk++){
      bf16x8 af[2], bfr[4];
      #pragma unroll
      for (int ms=0; ms<2; ms++) af[ms]  = *(const bf16x8*)&Al[aoff[ms][kk]];
      #pragma unroll
      for (int ns=0; ns<4; ns++) bfr[ns] = *(const bf16x8*)&Wl[woff[ns][kk]];
      #pragma unroll
      for (int ms=0; ms<2; ms++)
        #pragma unroll
        for (int ns=0; ns<4; ns++)
          acc[ms][ns] = __builtin_amdgcn_mfma_f32_16x16x32_bf16(af[ms], bfr[ns], acc[ms][ns], 0,0,0);
    }
    __syncthreads();
  }
  #pragma unroll
  for (int ms=0; ms<2; ms++){
    #pragma unroll
    for (int ns=0; ns<4; ns++){
      int c = col0 + 64*wx + 16*ns + ln;
      float wb = Wb[c];
      #pragma unroll
      for (int i=0;i<4;i++){
        int r = row0 + 32*wy + 16*ms + quad*4 + i;
        float val = acc[ms][ns][i] + wb;
        if (EPI == EPI_GELU) val = 0.5f*val*(1.f + erff(val*0.70710678f));
        o_u16[(size_t)r*ldc + c] = f2b(val);
      }
    }
  }
}

// ---------------- 128x128-tile split-K GEMM -> bf16 partials (4 slices)
__global__ __launch_bounds__(256) void k_gemm(const u16* __restrict__ A,
    const u16* __restrict__ W, int K, int Kslice, int ldc,
    u16* __restrict__ part)
{
  __shared__ __align__(16) u16 Al[128*64];
  __shared__ __align__(16) u16 Wl[128*64];
  int row0 = blockIdx.y*128, col0 = blockIdx.x*128;
  int tid = threadIdx.x;
  int w = tid >> 6, lane = tid & 63, ln = lane & 15, quad = lane >> 4;
  int wy = w >> 1, wx = w & 1;
  int srow = tid >> 3;
  int schunk = (tid & 7) ^ (srow & 7);
  const u16* Ag = A + (size_t)(row0 + srow)*K + schunk*8;
  const u16* Wg = W + (size_t)(col0 + srow)*K + schunk*8;
  int aoff[4][2], woff[4][2];
  #pragma unroll
  for (int ms=0; ms<4; ms++){
    int r = 64*wy + 16*ms + ln;
    #pragma unroll
    for (int kk=0; kk<2; kk++)
      aoff[ms][kk] = r*64 + (((kk*4+quad) ^ (ln&7))*8);
  }
  #pragma unroll
  for (int ns=0; ns<4; ns++){
    int r = 64*wx + 16*ns + ln;
    #pragma unroll
    for (int kk=0; kk<2; kk++)
      woff[ns][kk] = r*64 + (((kk*4+quad) ^ (ln&7))*8);
  }
  f32x4 acc[4][4] = {};
  int kbeg = blockIdx.z * Kslice;
  for (int k0 = kbeg; k0 < kbeg + Kslice; k0 += 64){
    #pragma unroll
    for (int i=0;i<4;i++){
      gload16(Ag + k0 + (size_t)(32*i)*K, Al + i*2048 + tid*8);
      gload16(Wg + k0 + (size_t)(32*i)*K, Wl + i*2048 + tid*8);
    }
    __syncthreads();
    #pragma unroll
    for (int kk=0; kk<2; kk++){
      bf16x8 af[4], bfr[4];
      #pragma unroll
      for (int ms=0; ms<4; ms++) af[ms]  = *(const bf16x8*)&Al[aoff[ms][kk]];
      #pragma unroll
      for (int ns=0; ns<4; ns++) bfr[ns] = *(const bf16x8*)&Wl[woff[ns][kk]];
      #pragma unroll
      for (int ms=0; ms<4; ms++)
        #pragma unroll
        for (int ns=0; ns<4; ns++)
          acc[ms][ns] = __builtin_amdgcn_mfma_f32_16x16x32_bf16(af[ms], bfr[ns], acc[ms][ns], 0,0,0);
    }
    __syncthreads();
  }
  u16* pbase = part + (size_t)blockIdx.z*M_*ldc;
  #pragma unroll
  for (int ms=0; ms<4; ms++){
    #pragma unroll
    for (int ns=0; ns<4; ns++){
      int c = col0 + 64*wx + 16*ns + ln;
      #pragma unroll
      for (int i=0;i<4;i++){
        int r = row0 + 64*wy + 16*ms + quad*4 + i;
        pbase[(size_t)r*ldc + c] = f2b(acc[ms][ns][i]);
      }
    }
  }
}

// ---------------- 4-slice reduce + bias + gate + residual -> f32 out
template<int GIDX>
__global__ __launch_bounds__(256) void k_red4(const u16* __restrict__ part,
    const float* __restrict__ Wb, const float* __restrict__ mod,
    const float* __restrict__ resid, float* __restrict__ outp)
{
  size_t i = ((size_t)blockIdx.x*256 + threadIdx.x)*4;
  int c = (int)(i & 1023); int r = (int)(i >> 10); int b = r >> 9;
  uint2 a0 = *(const uint2*)(part + i);
  uint2 a1 = *(const uint2*)(part + (size_t)M_*D_ + i);
  uint2 a2 = *(const uint2*)(part + (size_t)2*M_*D_ + i);
  uint2 a3 = *(const uint2*)(part + (size_t)3*M_*D_ + i);
  float4 pv;
  pv.x = b2f((u16)(a0.x&0xffff)) + b2f((u16)(a1.x&0xffff)) + b2f((u16)(a2.x&0xffff)) + b2f((u16)(a3.x&0xffff));
  pv.y = b2f((u16)(a0.x>>16))    + b2f((u16)(a1.x>>16))    + b2f((u16)(a2.x>>16))    + b2f((u16)(a3.x>>16));
  pv.z = b2f((u16)(a0.y&0xffff)) + b2f((u16)(a1.y&0xffff)) + b2f((u16)(a2.y&0xffff)) + b2f((u16)(a3.y&0xffff));
  pv.w = b2f((u16)(a0.y>>16))    + b2f((u16)(a1.y>>16))    + b2f((u16)(a2.y>>16))    + b2f((u16)(a3.y>>16));
  float4 x4 = *(const float4*)(resid + i);
  float4 bi = *(const float4*)(Wb + c);
  float4 g4 = *(const float4*)(mod + b*6*D_ + GIDX*D_ + c);
  float4 o;
  o.x = x4.x + g4.x*(pv.x + bi.x);
  o.y = x4.y + g4.y*(pv.y + bi.y);
  o.z = x4.z + g4.z*(pv.z + bi.z);
  o.w = x4.w + g4.w*(pv.w + bi.w);
  *(float4*)(outp + i) = o;
}

// ---------------- PROJ 4-slice reduce + gate_s + residual -> xm, LN2+mod -> xn
__global__ __launch_bounds__(256) void k_redln(const u16* __restrict__ part,
    const float* __restrict__ Wb, const float* __restrict__ mod,
    const float* __restrict__ resid, const float* __restrict__ g,
    const float* __restrict__ be, float* __restrict__ xm, u16* __restrict__ xn)
{
  int row = blockIdx.x, b = row >> 9, tid = threadIdx.x;
  size_t i = (size_t)row*D_ + tid*4;
  int c = tid*4;
  uint2 a0 = *(const uint2*)(part + i);
  uint2 a1 = *(const uint2*)(part + (size_t)M_*D_ + i);
  uint2 a2 = *(const uint2*)(part + (size_t)2*M_*D_ + i);
  uint2 a3 = *(const uint2*)(part + (size_t)3*M_*D_ + i);
  float4 pv;
  pv.x = b2f((u16)(a0.x&0xffff)) + b2f((u16)(a1.x&0xffff)) + b2f((u16)(a2.x&0xffff)) + b2f((u16)(a3.x&0xffff));
  pv.y = b2f((u16)(a0.x>>16))    + b2f((u16)(a1.x>>16))    + b2f((u16)(a2.x>>16))    + b2f((u16)(a3.x>>16));
  pv.z = b2f((u16)(a0.y&0xffff)) + b2f((u16)(a1.y&0xffff)) + b2f((u16)(a2.y&0xffff)) + b2f((u16)(a3.y&0xffff));
  pv.w = b2f((u16)(a0.y>>16))    + b2f((u16)(a1.y>>16))    + b2f((u16)(a2.y>>16))    + b2f((u16)(a3.y>>16));
  float4 x4 = *(const float4*)(resid + i);
  float4 bi = *(const float4*)(Wb + c);
  float4 g4 = *(const float4*)(mod + b*6*D_ + 2*D_ + c);
  float4 mid;
  mid.x = x4.x + g4.x*(pv.x + bi.x);
  mid.y = x4.y + g4.y*(pv.y + bi.y);
  mid.z = x4.z + g4.z*(pv.z + bi.z);
  mid.w = x4.w + g4.w*(pv.w + bi.w);
  *(float4*)(xm + i) = mid;
  float s = mid.x+mid.y+mid.z+mid.w;
  float s2 = mid.x*mid.x+mid.y*mid.y+mid.z*mid.z+mid.w*mid.w;
  #pragma unroll
  for (int o=32;o>0;o>>=1){ s += __shfl_down(s,o); s2 += __shfl_down(s2,o); }
  __shared__ float rs[4], rs2[4];
  int w = tid >> 6;
  if ((tid & 63)==0){ rs[w]=s; rs2[w]=s2; }
  __syncthreads();
  s = rs[0]+rs[1]+rs[2]+rs[3]; s2 = rs2[0]+rs2[1]+rs2[2]+rs2[3];
  float mu = s * (1.f/D_);
  float var = s2 * (1.f/D_) - mu*mu;
  float rstd = rsqrtf(var + 1e-5f);
  const float* mrow = mod + b*6*D_;
  float4 gg = *(const float4*)(g + c);
  float4 bb = *(const float4*)(be + c);
  float4 sc = *(const float4*)(mrow + 4*D_ + c);
  float4 sh = *(const float4*)(mrow + 3*D_ + c);
  u16 o[4];
  o[0] = f2b(((mid.x-mu)*rstd*gg.x + bb.x)*(1.f+sc.x) + sh.x);
  o[1] = f2b(((mid.y-mu)*rstd*gg.y + bb.y)*(1.f+sc.y) + sh.y);
  o[2] = f2b(((mid.z-mu)*rstd*gg.z + bb.z)*(1.f+sc.z) + sh.z);
  o[3] = f2b(((mid.w-mu)*rstd*gg.w + bb.w)*(1.f+sc.w) + sh.w);
  *(uint2*)(xn + i) = *(const uint2*)o;
}

// ---------------- flash attention: block = (nt64, h, b), 4 waves, 64 q-rows
__global__ __launch_bounds__(256) void k_attn(const u16* __restrict__ qkv,
    const u16* __restrict__ biasbuf, u16* __restrict__ attn_out)
{
  __shared__ __align__(16) u16 Qs[64*72];
  __shared__ __align__(16) u16 Ks[64*72];
  __shared__ __align__(16) u16 Vt[64*72];
  __shared__ __align__(16) u16 Ps[4*16*72];
  int nt = blockIdx.x, h = blockIdx.y, b = blockIdx.z;
  int n0 = nt*64;
  int tid = threadIdx.x;
  int w = tid >> 6, lane = tid & 63, ln = lane & 15, quad = lane >> 4;

  {
    int row = tid >> 2, cb = (tid & 3)*16;
    const u16* src = qkv + (size_t)(b*N_ + n0 + row)*3072 + h*64 + cb;
    uint4 q0 = *(const uint4*)src, q1 = *(const uint4*)(src+8);
    uint4* dst = (uint4*)&Qs[row*72 + cb];
    dst[0] = q0; dst[1] = q1;
  }
  __syncthreads();
  bf16x8 qf[2];
  qf[0] = *(const bf16x8*)&Qs[(16*w+ln)*72 + quad*8];
  qf[1] = *(const bf16x8*)&Qs[(16*w+ln)*72 + 32 + quad*8];

  f32x4 oacc[4] = {};
  float rmax[4] = {-3e38f,-3e38f,-3e38f,-3e38f};
  float rsum[4] = {0.f,0.f,0.f,0.f};
  const u16* bp = biasbuf + (((size_t)(b*H_ + h)*N_) + n0 + 16*w)*N_ + ln;

  for (int mt = 0; mt < 8; mt++){
    __syncthreads();
    {
      int r = tid >> 2, cb = (tid & 3)*16;
      const u16* kp = qkv + (size_t)(b*N_ + mt*64 + r)*3072 + 1024 + h*64 + cb;
      uint4 k0 = *(const uint4*)kp, k1 = *(const uint4*)(kp+8);
      uint4* kd = (uint4*)&Ks[r*72 + cb];
      kd[0] = k0; kd[1] = k1;
      const u16* vp = qkv + (size_t)(b*N_ + mt*64 + r)*3072 + 2048 + h*64 + cb;
      uint4 v0 = *(const uint4*)vp, v1 = *(const uint4*)(vp+8);
      u16 ve[16];
      *(uint4*)&ve[0] = v0; *(uint4*)&ve[8] = v1;
      #pragma unroll
      for (int j=0;j<16;j++) Vt[(cb+j)*72 + r] = ve[j];
    }
    __syncthreads();

    u16 bl[4][4];
    #pragma unroll
    for (int cs=0; cs<4; cs++)
      #pragma unroll
      for (int i=0;i<4;i++)
        bl[cs][i] = bp[(size_t)(quad*4+i)*N_ + mt*64 + 16*cs];

    f32x4 s[4];
    #pragma unroll
    for (int cs=0; cs<4; cs++){
      bf16x8 k0f = *(const bf16x8*)&Ks[(16*cs+ln)*72 + quad*8];
      bf16x8 k1f = *(const bf16x8*)&Ks[(16*cs+ln)*72 + 32 + quad*8];
      f32x4 z = {};
      z = __builtin_amdgcn_mfma_f32_16x16x32_bf16(qf[0], k0f, z, 0,0,0);
      z = __builtin_amdgcn_mfma_f32_16x16x32_bf16(qf[1], k1f, z, 0,0,0);
      s[cs] = z;
    }
    #pragma unroll
    for (int cs=0; cs<4; cs++)
      #pragma unroll
      for (int i=0;i<4;i++)
        s[cs][i] = s[cs][i]*0.125f + b2f(bl[cs][i]);

    #pragma unroll
    for (int i=0;i<4;i++){
      float tm = fmaxf(fmaxf(s[0][i], s[1][i]), fmaxf(s[2][i], s[3][i]));
      #pragma unroll
      for (int o=1;o<16;o<<=1) tm = fmaxf(tm, __shfl_xor(tm, o));
      float nm = fmaxf(rmax[i], tm);
      float alpha = __expf(rmax[i] - nm);
      rmax[i] = nm;
      float ps = 0.f;
      #pragma unroll
      for (int cs=0; cs<4; cs++){
        float p = __expf(s[cs][i] - nm);
        s[cs][i] = p; ps += p;
      }
      #pragma unroll
      for (int o=1;o<16;o<<=1) ps += __shfl_xor(ps, o);
      rsum[i] = rsum[i]*alpha + ps;
      #pragma unroll
      for (int ds=0; ds<4; ds++) oacc[ds][i] *= alpha;
    }

    #pragma unroll
    for (int cs=0; cs<4; cs++)
      #pragma unroll
      for (int i=0;i<4;i++)
        Ps[w*1152 + (quad*4+i)*72 + 16*cs + ln] = f2b(s[cs][i]);

    bf16x8 pf0 = *(const bf16x8*)&Ps[w*1152 + ln*72 + quad*8];
    bf16x8 pf1 = *(const bf16x8*)&Ps[w*1152 + ln*72 + 32 + quad*8];
    #pragma unroll
    for (int ds=0; ds<4; ds++){
      bf16x8 v0f = *(const bf16x8*)&Vt[(16*ds+ln)*72 + quad*8];
      bf16x8 v1f = *(const bf16x8*)&Vt[(16*ds+ln)*72 + 32 + quad*8];
      oacc[ds] = __builtin_amdgcn_mfma_f32_16x16x32_bf16(pf0, v0f, oacc[ds], 0,0,0);
      oacc[ds] = __builtin_amdgcn_mfma_f32_16x16x32_bf16(pf1, v1f, oacc[ds], 0,0,0);
    }
  }

  #pragma unroll
  for (int i=0;i<4;i++){
    float inv = 1.f / rsum[i];
    int r = b*N_ + n0 + 16*w + quad*4 + i;
    #pragma unroll
    for (int ds=0; ds<4; ds++)
      attn_out[(size_t)r*D_ + h*64 + 16*ds + ln] = f2b(oacc[ds][i]*inv);
  }
}

extern "C" void kernel_launch(void* const* d_in, const int* in_sizes, int n_in,
                              void* d_out, int out_size, void* d_ws, size_t ws_size,
                              hipStream_t stream) {
  const float* x      = (const float*)d_in[0];
  const float* t_emb  = (const float*)d_in[1];
  const float* rel    = (const float*)d_in[2];
  const int*   amask  = (const int*)d_in[3];
  const float* w_ada  = (const float*)d_in[4];
  const float* b_ada  = (const float*)d_in[5];
  const float* g1     = (const float*)d_in[6];
  const float* beta1  = (const float*)d_in[7];
  const float* g2     = (const float*)d_in[8];
  const float* beta2  = (const float*)d_in[9];
  const float* w_qkv  = (const float*)d_in[10];
  const float* b_qkv  = (const float*)d_in[11];
  const float* w_proj = (const float*)d_in[12];
  const float* b_proj = (const float*)d_in[13];
  const float* w_rp1  = (const float*)d_in[14];
  const float* b_rp1  = (const float*)d_in[15];
  const float* w_rp2  = (const float*)d_in[16];
  const float* b_rp2  = (const float*)d_in[17];
  const float* w_fc1  = (const float*)d_in[18];
  const float* b_fc1  = (const float*)d_in[19];
  const float* w_fc2  = (const float*)d_in[20];
  const float* b_fc2  = (const float*)d_in[21];
  float* outp = (float*)d_out;

  const size_t MB = 1u<<20;
  char* wsb = (char*)d_ws;
  float* mod   = (float*)(wsb);
  u16*  xn     = (u16*) (wsb + 131072);
  float* xm    = (float*)(wsb + 131072 + 4*MB);
  u16*  wqkvb  = (u16*) (wsb + 131072 + 12*MB);
  u16*  wprojb = (u16*) (wsb + 131072 + 18*MB);
  u16*  wfc1b  = (u16*) (wsb + 131072 + 20*MB);
  u16*  wfc2b  = (u16*) (wsb + 131072 + 28*MB);
  u16*  qkvb   = (u16*) (wsb + 131072 + 36*MB);
  u16*  biasb  = (u16*) (wsb + 131072 + 48*MB);
  u16*  hb     = (u16*) (wsb + 131072 + 80*MB);
  u16*  parts  = (u16*) (wsb + 131072 + 96*MB);

  // 1) converts + adaLN mod (high-MLP streaming launch)
  k_cvtmod<<<1632, 256, 0, stream>>>(
      w_qkv, wqkvb, w_proj, wprojb, w_fc1, wfc1b, w_fc2, wfc2b,
      t_emb, w_ada, b_ada, mod);
  // 2) rel-pos bias (heavy-LDS launch)
  k_bias<<<dim3(2, N_, B_), 256, 0, stream>>>(rel, amask, w_rp1, b_rp1, w_rp2, b_rp2, biasb);
  // 3) LN1
  k_lnmod<<<M_, 256, 0, stream>>>(x, g1, beta1, mod, 0, 1, xn);
  // 4) QKV 64x128 direct
  k_gemm64<EPI_PLAIN><<<dim3(3072/128, M_/64), 256, 0, stream>>>(
      xn, wqkvb, b_qkv, D_, 3072, qkvb);
  // 5) attention
  k_attn<<<dim3(8, H_, B_), 256, 0, stream>>>(qkvb, biasb, xn);
  // 6) PROJ split-K x4
  k_gemm<<<dim3(D_/128, M_/128, 4), 256, 0, stream>>>(
      xn, wprojb, D_, D_/4, D_, parts);
  // 7) PROJ reduce + LN2
  k_redln<<<M_, 256, 0, stream>>>(parts, b_proj, mod, x, g2, beta2, xm, xn);
  // 8) FC1 64x128 + GELU
  k_gemm64<EPI_GELU><<<dim3(HID_/128, M_/64), 256, 0, stream>>>(
      xn, wfc1b, b_fc1, D_, HID_, hb);
  // 9) FC2 split-K x4
  k_gemm<<<dim3(D_/128, M_/128, 4), 256, 0, stream>>>(
      hb, wfc2b, HID_, HID_/4, D_, parts);
  // 10) FC2 reduce -> out
  k_red4<5><<<2048, 256, 0, stream>>>(parts, b_fc2, mod, xm, outp);
}